// Round 2
// baseline (257.216 us; speedup 1.0000x reference)
//
#include <hip/hip_runtime.h>
#include <hip/hip_bf16.h>

// GroupEmbedding: out[g,d] = sum_u ( (sum_m item_emb[beh_ids[g,u,m],d]*cnt[g,u,m])
//                                    * user_emb[group_user[g,u],d]
//                                    * 0.5*dot(sim[target[g]], sim[group_user[g,u]]) )
// G=4096, U=50, M=20, D=S=64.
//
// Design: 1 block (4 waves) per group; wave handles users u = wave, wave+4, ...
// lane == dim d == sim dim s. Each item-row gather is one coalesced 256B
// global_load_dword across the wave. Sim dot via 6-step __shfl_xor (wave=64).

constexpr int G = 4096;
constexpr int U = 50;
constexpr int M = 20;
constexpr int D = 64;
constexpr int S = 64;
constexpr float FACTOR = 0.5f;

__global__ __launch_bounds__(256) void group_embedding_kernel(
    const int*   __restrict__ group_user,       // [G,U]
    const int*   __restrict__ behavior_ids,     // [G,U,M]
    const float* __restrict__ behavior_counts,  // [G,U,M]
    const int*   __restrict__ target_user,      // [G]
    const float* __restrict__ similarity_vec,   // [USER_NUM,S]
    const float* __restrict__ user_emb_w,       // [USER_NUM,D]
    const float* __restrict__ item_emb_w,       // [ITEM_NUM,D]
    float*       __restrict__ out)              // [G,D]
{
    const int g    = blockIdx.x;
    const int tid  = threadIdx.x;
    const int wave = tid >> 6;   // 0..3
    const int lane = tid & 63;   // == d == s

    // Target-user similarity element for this lane (uniform per block).
    const int   tgt  = target_user[g];
    const float tsim = similarity_vec[(size_t)tgt * S + lane];

    float acc = 0.0f;  // out[g, lane] partial for this wave

    // unroll 2: interleave two users' gather batches (40 independent VMEM in
    // flight per window) and overlap the serial shfl sim-reduction of user u
    // with user u+4's gathers.
    #pragma unroll 2
    for (int u = wave; u < U; u += 4) {
        const int gu = group_user[g * U + u];

        // --- similarity weight: 0.5 * dot(sim[tgt], sim[gu]) over 64 dims ---
        float p = tsim * similarity_vec[(size_t)gu * S + lane];
        #pragma unroll
        for (int off = 32; off > 0; off >>= 1)
            p += __shfl_xor(p, off);
        const float sim = FACTOR * p;   // wave-uniform value, all lanes

        // --- weighted behavior sum: sum_m item_emb[id_m, lane] * cnt_m ---
        const int bbase = (g * U + u) * M;
        int   ids [M];
        float cnts[M];
        #pragma unroll
        for (int m = 0; m < M; ++m) {
            ids [m] = behavior_ids   [bbase + m];   // wave-uniform (scalarizable)
            cnts[m] = behavior_counts[bbase + m];
        }
        float ub = 0.0f;
        #pragma unroll
        for (int m = 0; m < M; ++m) {
            // coalesced 256B row gather: lane d reads item_emb_w[id*64 + d]
            ub = fmaf(item_emb_w[(size_t)ids[m] * D + lane], cnts[m], ub);
        }

        const float ue = user_emb_w[(size_t)gu * D + lane];
        acc = fmaf(ub * ue, sim, acc);
    }

    // --- reduce the 4 wave partials through LDS (stride 64, conflict-free) ---
    __shared__ float red[4][D];
    red[wave][lane] = acc;
    __syncthreads();
    if (wave == 0) {
        out[(size_t)g * D + lane] =
            red[0][lane] + red[1][lane] + red[2][lane] + red[3][lane];
    }
}

extern "C" void kernel_launch(void* const* d_in, const int* in_sizes, int n_in,
                              void* d_out, int out_size, void* d_ws, size_t ws_size,
                              hipStream_t stream) {
    const int*   group_user      = (const int*)  d_in[0];
    const int*   behavior_ids    = (const int*)  d_in[1];
    const float* behavior_counts = (const float*)d_in[2];
    const int*   target_user     = (const int*)  d_in[3];
    const float* similarity_vec  = (const float*)d_in[4];
    const float* user_emb_w      = (const float*)d_in[5];
    const float* item_emb_w      = (const float*)d_in[6];
    float*       out             = (float*)d_out;

    group_embedding_kernel<<<G, 256, 0, stream>>>(
        group_user, behavior_ids, behavior_counts, target_user,
        similarity_vec, user_emb_w, item_emb_w, out);
}